// Round 5
// baseline (86.396 us; speedup 1.0000x reference)
//
#include <hip/hip_runtime.h>
#include <math.h>

#define OUT_H 152
#define OUT_W 272
#define HW 41344
#define NOBJ 64
#define NB 8
#define NID 537
#define EMB 256

#define NIDBLK 512                 /* id blocks first: one per object */
#define NFBLK 162                  /* focal blocks per batch */
#define NFOCAL (NFBLK * NB)        /* 1296 */
#define NBLOCKS (NIDBLK + NFOCAL)  /* 1808 — all co-resident (< 2048) */

/* workspace word offsets (4-byte units) */
#define OF_FP    0                         /* 1296*3 focal partials */
#define OF_IDNLL (NFOCAL * 3)              /* 3888: 512 id NLL */
#define OF_REGP  (OF_IDNLL + 512)          /* 4400 */
#define OF_VISP  (OF_REGP + 512)           /* 4912 */
#define OF_VMV   (OF_VISP + 512)           /* 5424 */
#define OF_TOK   (OF_VMV + 512)            /* 5936: 1808 done-tokens */

#define TOKEN(b) (0x5AB00000u ^ (unsigned)(b))

__device__ inline float waveRedSum(float v) {
  for (int off = 32; off; off >>= 1) v += __shfl_down(v, off, 64);
  return v;
}
__device__ inline float waveRedMax(float v) {
  for (int off = 32; off; off >>= 1) v = fmaxf(v, __shfl_down(v, off, 64));
  return v;
}

__device__ __forceinline__ float ldAgent(const float* p) {
  return __hip_atomic_load(p, __ATOMIC_RELAXED, __HIP_MEMORY_SCOPE_AGENT);
}

struct PrepOut {
  float cxf, cyf, radius, inv2s2, vm, v;
  float wh[8];
  int ind, id;
};

__device__ __forceinline__ PrepOut prep_obj(const float* __restrict__ ann1,
                                            const float* __restrict__ ann2,
                                            int b, int i) {
  const float* a1 = ann1 + (b * NOBJ + i) * 8;
  const float* A2 = ann2 + b * NOBJ * 8;

  float cx_raw = a1[0] * (float)OUT_W;
  float cy_raw = a1[1] * (float)OUT_H;
  float w = a1[2] * (float)OUT_W;
  float h = a1[3] * (float)OUT_H;
  float x1 = cx_raw - 0.5f * w, y1 = cy_raw - 0.5f * h;
  float x2 = x1 + w, y2 = y1 + h;
  float cx = fminf(fmaxf(cx_raw, 0.f), (float)(OUT_W - 1));
  float cy = fminf(fmaxf(cy_raw, 0.f), (float)(OUT_H - 1));
  int ctx = (int)cx, cty = (int)cy;

  float hc = ceilf(h), wc = ceilf(w);
  float b1 = hc + wc;
  float c1 = wc * hc * 0.3f / 1.7f;
  float r1 = (b1 + sqrtf(fmaxf(b1 * b1 - 4.f * c1, 0.f))) * 0.5f;
  float b2 = 2.f * (hc + wc);
  float c2 = 0.3f * wc * hc;
  float r2 = (b2 + sqrtf(fmaxf(b2 * b2 - 16.f * c2, 0.f))) * 0.5f;
  float b3 = -1.4f * (hc + wc);
  float c3 = -0.3f * wc * hc;
  float r3 = (b3 + sqrtf(fmaxf(b3 * b3 - 11.2f * c3, 0.f))) * 0.5f;
  float radius = fmaxf(floorf(fminf(fminf(r1, r2), r3)), 0.f);
  float sigma = (2.f * radius + 1.f) / 6.f;

  PrepOut P;
  P.cxf = (float)ctx;
  P.cyf = (float)cty;
  P.radius = radius;
  P.inv2s2 = 1.f / (2.f * sigma * sigma);

  float pid = a1[5];
  int jm = -1;
  for (int j = 0; j < NOBJ; ++j) {
    if (A2[j * 8 + 5] == pid) { jm = j; break; }
  }
  bool has = (jm >= 0);
  const float* t1 = A2 + (has ? jm : 0) * 8;
  float cx2 = t1[0] * (float)OUT_W, cy2 = t1[1] * (float)OUT_H;
  float w2 = t1[2] * (float)OUT_W, h2 = t1[3] * (float)OUT_H;
  float x1t = cx2 - 0.5f * w2, y1t = cy2 - 0.5f * h2;
  float x2t = x1t + w2, y2t = y1t + h2;

  bool valid = has && (h > 0.f) && (w > 0.f) && (h2 > 0.f) && (w2 > 0.f);
  float vm = valid ? 1.f : 0.f;
  P.vm = vm;
  P.v = a1[6] * vm;
  P.wh[0] = (P.cxf - x1) * vm;  P.wh[1] = (x2 - P.cxf) * vm;
  P.wh[2] = (P.cyf - y1) * vm;  P.wh[3] = (y2 - P.cyf) * vm;
  P.wh[4] = (P.cxf - x1t) * vm; P.wh[5] = (x2t - P.cxf) * vm;
  P.wh[6] = (P.cyf - y1t) * vm; P.wh[7] = (y2t - P.cyf) * vm;
  P.ind = valid ? (cty * OUT_W + ctx) : 0;
  P.id = valid ? (int)pid : 0;
  return P;
}

__global__ void __launch_bounds__(256)
main_kernel(const float* __restrict__ cls,
            const float* __restrict__ reg,
            const float* __restrict__ viss,
            const float* __restrict__ identis,
            const float* __restrict__ W_id,
            const float* __restrict__ b_id,
            const float* __restrict__ ann1,
            const float* __restrict__ ann2,
            const float* __restrict__ s_det,
            const float* __restrict__ s_id,
            float* __restrict__ F,
            float* __restrict__ out) {
  int t = threadIdx.x;
  int wid = t >> 6, lane = t & 63;

  if (blockIdx.x < NIDBLK) {
    /* ---------- id + reg/vis branch: one block per object ---------- */
    int o = blockIdx.x;
    int b = o >> 6, i = o & 63;
    PrepOut P = prep_obj(ann1, ann2, b, i);

    if (wid == 0) {
      float rv = 0.f, vv = 0.f;
      if (lane < 8) {
        float pred = reg[(b * 8 + lane) * HW + P.ind];
        float d = fabsf(pred * P.vm - P.wh[lane]);
        rv = (d < 1.f) ? 0.5f * d * d : d - 0.5f;
      } else if (lane == 8) {
        float s = 1.f / (1.f + __expf(-viss[b * HW + P.ind]));
        s = fminf(fmaxf(s, 1e-4f), 0.9999f);
        float d = fabsf(s * P.vm - P.v);
        vv = (d < 1.f) ? 0.5f * d * d : d - 0.5f;
      }
      rv = waveRedSum(rv);
      vv = waveRedSum(vv);
      if (lane == 0) {
        F[OF_REGP + o] = rv;
        F[OF_VISP + o] = vv;
        F[OF_VMV + o]  = P.vm;
      }
    }

    if (P.vm == 0.f) {               /* block-uniform */
      if (t == 0) F[OF_IDNLL + o] = 0.f;
    } else {
      __shared__ float shf[EMB];
      __shared__ float slog[544];
      __shared__ float red4[4];

      float f = identis[(size_t)b * EMB * HW + (size_t)t * HW + P.ind];
      float n2 = waveRedSum(f * f);
      if (lane == 0) red4[wid] = n2;
      __syncthreads();
      float norm2 = red4[0] + red4[1] + red4[2] + red4[3];
      const float EMB_SCALE = 1.41421356237309515f * logf(536.0f);
      float scale = EMB_SCALE / fmaxf(sqrtf(norm2), 1e-12f);
      shf[t] = f * scale;
      __syncthreads();

      /* logits GEMV: row per 16-lane group, coalesced float4 */
      int g = lane >> 4, j = lane & 15;
      float4 e0 = *(const float4*)&shf[j * 4];
      float4 e1 = *(const float4*)&shf[j * 4 + 64];
      float4 e2 = *(const float4*)&shf[j * 4 + 128];
      float4 e3 = *(const float4*)&shf[j * 4 + 192];
      for (int it = 0; it < 34; ++it) {
        int r = wid * 4 + it * 16 + g;
        bool ok = (r < NID);
        float acc = 0.f;
        if (ok) {
          const float* wr = W_id + (size_t)r * EMB + j * 4;
          float4 w0 = *(const float4*)(wr);
          float4 w1 = *(const float4*)(wr + 64);
          float4 w2 = *(const float4*)(wr + 128);
          float4 w3 = *(const float4*)(wr + 192);
          acc = w0.x * e0.x + w0.y * e0.y + w0.z * e0.z + w0.w * e0.w
              + w1.x * e1.x + w1.y * e1.y + w1.z * e1.z + w1.w * e1.w
              + w2.x * e2.x + w2.y * e2.y + w2.z * e2.z + w2.w * e2.w
              + w3.x * e3.x + w3.y * e3.y + w3.z * e3.z + w3.w * e3.w;
        }
        acc += __shfl_xor(acc, 8, 64);
        acc += __shfl_xor(acc, 4, 64);
        acc += __shfl_xor(acc, 2, 64);
        acc += __shfl_xor(acc, 1, 64);
        if (ok && j == 0) slog[r] = acc + b_id[r];
      }
      __syncthreads();

      float mx = -1e30f;
      for (int c = t; c < NID; c += 256) mx = fmaxf(mx, slog[c]);
      mx = waveRedMax(mx);
      __syncthreads();
      if (lane == 0) red4[wid] = mx;
      __syncthreads();
      mx = fmaxf(fmaxf(red4[0], red4[1]), fmaxf(red4[2], red4[3]));

      float se = 0.f;
      for (int c = t; c < NID; c += 256) se += __expf(slog[c] - mx);
      se = waveRedSum(se);
      __syncthreads();
      if (lane == 0) red4[wid] = se;
      __syncthreads();

      if (t == 0) {
        float sesum = red4[0] + red4[1] + red4[2] + red4[3];
        float lse = mx + __logf(sesum);
        F[OF_IDNLL + o] = -P.v * (slog[P.id] - lse);
      }
    }
  } else {
    /* ---------- focal branch ---------- */
    int blk = blockIdx.x - NIDBLK;
    int b = blk / NFBLK;
    int bx = blk - b * NFBLK;
    int p = bx * 256 + t;

    __shared__ float s_ctx[64], s_cty[64], s_rad[64], s_inv[64];
    if (t < 64) {
      PrepOut P = prep_obj(ann1, ann2, b, t);
      s_ctx[t] = P.cxf;
      s_cty[t] = P.cyf;
      s_rad[t] = P.radius;
      s_inv[t] = P.inv2s2;
    }
    __syncthreads();

    float pos_l = 0.f, neg_l = 0.f, npos = 0.f;
    if (p < HW) {
      float xf = (float)(p % OUT_W);
      float yf = (float)(p / OUT_W);
      float gt = 0.f;
      #pragma unroll 8
      for (int o = 0; o < 64; ++o) {
        float dy = yf - s_cty[o];
        float dx = xf - s_ctx[o];
        float r = s_rad[o];
        if (fabsf(dy) <= r && fabsf(dx) <= r) {
          gt = fmaxf(gt, __expf(-(dy * dy + dx * dx) * s_inv[o]));
        }
      }
      float x = cls[b * HW + p];
      float pr = 1.f / (1.f + __expf(-x));
      pr = fminf(fmaxf(pr, 1e-4f), 0.9999f);
      if (gt == 1.f) {
        float om = 1.f - pr;
        pos_l = __logf(pr) * om * om;
        npos = 1.f;
      } else {
        float omg = 1.f - gt;
        float w4 = omg * omg;
        w4 *= w4;
        neg_l = __logf(1.f - pr) * pr * pr * w4;
      }
    }

    __shared__ float red[3][4];
    float a = waveRedSum(pos_l);
    float c = waveRedSum(neg_l);
    float n = waveRedSum(npos);
    if (lane == 0) { red[0][wid] = a; red[1][wid] = c; red[2][wid] = n; }
    __syncthreads();
    if (t == 0) {
      float pa = 0.f, pc = 0.f, pn = 0.f;
      for (int k = 0; k < 4; ++k) { pa += red[0][k]; pc += red[1][k]; pn += red[2][k]; }
      F[OF_FP + blk * 3 + 0] = pa;
      F[OF_FP + blk * 3 + 1] = pc;
      F[OF_FP + blk * 3 + 2] = pn;
    }
  }

  /* ---------- publish done-token ---------- */
  __syncthreads();                       /* all block stores drained (vmcnt) */
  if (t == 0) {
    __threadfence();                     /* device-scope release */
    unsigned* tok = (unsigned*)F + OF_TOK;
    __hip_atomic_store(&tok[blockIdx.x], TOKEN(blockIdx.x),
                       __ATOMIC_RELEASE, __HIP_MEMORY_SCOPE_AGENT);
  }

  /* ---------- block 0 finalizes ---------- */
  if (blockIdx.x == 0) {
    unsigned* tok = (unsigned*)F + OF_TOK;
    for (int i = t; i < NBLOCKS; i += 256) {
      while (__hip_atomic_load(&tok[i], __ATOMIC_ACQUIRE,
                               __HIP_MEMORY_SCOPE_AGENT) != TOKEN(i)) {
        __builtin_amdgcn_s_sleep(2);
      }
    }
    __syncthreads();

    __shared__ float L[8][4];
    for (int half = 0; half < 2; ++half) {
      int b = wid * 2 + half;
      float pa = 0.f, pc = 0.f, pn = 0.f;
      for (int e = lane; e < NFBLK; e += 64) {
        const float* fp = F + OF_FP + (b * NFBLK + e) * 3;
        pa += ldAgent(fp + 0); pc += ldAgent(fp + 1); pn += ldAgent(fp + 2);
      }
      pa = waveRedSum(pa);
      pc = waveRedSum(pc);
      pn = waveRedSum(pn);
      float rs = waveRedSum(ldAgent(F + OF_REGP + b * 64 + lane));
      float vs = waveRedSum(ldAgent(F + OF_VISP + b * 64 + lane));
      float ms = waveRedSum(ldAgent(F + OF_VMV  + b * 64 + lane));
      float iv = waveRedSum(ldAgent(F + OF_IDNLL + b * 64 + lane));
      if (lane == 0) {
        L[b][0] = (pn > 0.f) ? (-(pa + pc) / fmaxf(pn, 1.f)) : (-pc);
        L[b][1] = rs / (ms + 0.0001f);
        L[b][2] = vs / (ms + 0.0001f);
        L[b][3] = iv / fmaxf(ms, 1.f);
      }
    }
    __syncthreads();
    if (t == 0) {
      float cl = 0.f, rl = 0.f, vl = 0.f, il = 0.f;
      for (int k = 0; k < 8; ++k) {
        cl += L[k][0]; rl += L[k][1]; vl += L[k][2]; il += L[k][3];
      }
      out[0] = cl / 8.f;
      out[1] = rl / 8.f;
      out[2] = vl / 8.f;
      out[3] = il / 8.f;
      out[4] = s_det[0];
      out[5] = s_id[0];
    }
  }
}

extern "C" void kernel_launch(void* const* d_in, const int* in_sizes, int n_in,
                              void* d_out, int out_size, void* d_ws, size_t ws_size,
                              hipStream_t stream) {
  const float* cls     = (const float*)d_in[0];
  const float* reg     = (const float*)d_in[1];
  const float* viss    = (const float*)d_in[2];
  const float* identis = (const float*)d_in[3];
  const float* ann1    = (const float*)d_in[4];
  const float* ann2    = (const float*)d_in[5];
  const float* W_id    = (const float*)d_in[6];
  const float* b_id    = (const float*)d_in[7];
  const float* s_det   = (const float*)d_in[8];
  const float* s_id    = (const float*)d_in[9];
  float* F = (float*)d_ws;

  main_kernel<<<NBLOCKS, 256, 0, stream>>>(cls, reg, viss, identis,
                                           W_id, b_id, ann1, ann2,
                                           s_det, s_id, F, (float*)d_out);
}

// Round 6
// 60.912 us; speedup vs baseline: 1.4184x; 1.4184x over previous
//
#include <hip/hip_runtime.h>
#include <math.h>

#define OUT_H 152
#define OUT_W 272
#define HW 41344
#define NOBJ 64
#define NB 8
#define NID 537
#define EMB 256

#define NFBLK 162                 /* focal blocks per batch: ceil(41344/256) */
#define NFOCAL (NFBLK * NB)       /* 1296 */
#define NIDBLK (NB * NOBJ)        /* 512 */

/* workspace float offsets — every slot written by kernel A before B reads */
#define OF_FP    0                /* 1296*3 focal partials (pos,neg,np) */
#define OF_IDNLL (NFOCAL * 3)     /* 512 per-object id NLL */

__device__ inline float waveRedSum(float v) {
  for (int off = 32; off; off >>= 1) v += __shfl_down(v, off, 64);
  return v;
}
__device__ inline float waveRedMax(float v) {
  for (int off = 32; off; off >>= 1) v = fmaxf(v, __shfl_down(v, off, 64));
  return v;
}

struct PrepOut {
  float cxf, cyf, radius, inv2s2, vm, v;
  float wh[8];
  int ind, id;
};

__device__ __forceinline__ PrepOut prep_obj(const float* __restrict__ ann1,
                                            const float* __restrict__ ann2,
                                            int b, int i) {
  const float* a1 = ann1 + (b * NOBJ + i) * 8;
  const float* A2 = ann2 + b * NOBJ * 8;

  float cx_raw = a1[0] * (float)OUT_W;
  float cy_raw = a1[1] * (float)OUT_H;
  float w = a1[2] * (float)OUT_W;
  float h = a1[3] * (float)OUT_H;
  float x1 = cx_raw - 0.5f * w, y1 = cy_raw - 0.5f * h;
  float x2 = x1 + w, y2 = y1 + h;
  float cx = fminf(fmaxf(cx_raw, 0.f), (float)(OUT_W - 1));
  float cy = fminf(fmaxf(cy_raw, 0.f), (float)(OUT_H - 1));
  int ctx = (int)cx, cty = (int)cy;

  float hc = ceilf(h), wc = ceilf(w);
  float b1 = hc + wc;
  float c1 = wc * hc * 0.3f / 1.7f;
  float r1 = (b1 + sqrtf(fmaxf(b1 * b1 - 4.f * c1, 0.f))) * 0.5f;
  float b2 = 2.f * (hc + wc);
  float c2 = 0.3f * wc * hc;
  float r2 = (b2 + sqrtf(fmaxf(b2 * b2 - 16.f * c2, 0.f))) * 0.5f;
  float b3 = -1.4f * (hc + wc);
  float c3 = -0.3f * wc * hc;
  float r3 = (b3 + sqrtf(fmaxf(b3 * b3 - 11.2f * c3, 0.f))) * 0.5f;
  float radius = fmaxf(floorf(fminf(fminf(r1, r2), r3)), 0.f);
  float sigma = (2.f * radius + 1.f) / 6.f;

  PrepOut P;
  P.cxf = (float)ctx;
  P.cyf = (float)cty;
  P.radius = radius;
  P.inv2s2 = 1.f / (2.f * sigma * sigma);

  float pid = a1[5];
  int jm = -1;
  for (int j = 0; j < NOBJ; ++j) {
    if (A2[j * 8 + 5] == pid) { jm = j; break; }
  }
  bool has = (jm >= 0);
  const float* t1 = A2 + (has ? jm : 0) * 8;
  float cx2 = t1[0] * (float)OUT_W, cy2 = t1[1] * (float)OUT_H;
  float w2 = t1[2] * (float)OUT_W, h2 = t1[3] * (float)OUT_H;
  float x1t = cx2 - 0.5f * w2, y1t = cy2 - 0.5f * h2;
  float x2t = x1t + w2, y2t = y1t + h2;

  bool valid = has && (h > 0.f) && (w > 0.f) && (h2 > 0.f) && (w2 > 0.f);
  float vm = valid ? 1.f : 0.f;
  P.vm = vm;
  P.v = a1[6] * vm;
  P.wh[0] = (P.cxf - x1) * vm;  P.wh[1] = (x2 - P.cxf) * vm;
  P.wh[2] = (P.cyf - y1) * vm;  P.wh[3] = (y2 - P.cyf) * vm;
  P.wh[4] = (P.cxf - x1t) * vm; P.wh[5] = (x2t - P.cxf) * vm;
  P.wh[6] = (P.cyf - y1t) * vm; P.wh[7] = (y2t - P.cyf) * vm;
  P.ind = valid ? (cty * OUT_W + ctx) : 0;
  P.id = valid ? (int)pid : 0;
  return P;
}

__global__ void __launch_bounds__(256)
main_kernel(const float* __restrict__ cls,
            const float* __restrict__ identis,
            const float* __restrict__ W_id,
            const float* __restrict__ b_id,
            const float* __restrict__ ann1,
            const float* __restrict__ ann2,
            float* __restrict__ F) {
  if (blockIdx.x < NFOCAL) {
    /* ---------- focal branch with object culling ---------- */
    int blk = blockIdx.x;
    int b = blk / NFBLK;
    int bx = blk - b * NFBLK;
    int p0 = bx * 256;
    int p = p0 + threadIdx.x;

    __shared__ unsigned s_pk[64];          /* ctx | cty<<9 | rad<<17 */
    __shared__ float s_inv[64];
    __shared__ unsigned long long s_mask;
    if (threadIdx.x < 64) {                /* exactly wave 0 */
      PrepOut P = prep_obj(ann1, ann2, b, threadIdx.x);
      int ctx = (int)P.cxf, cty = (int)P.cyf, r = (int)P.radius;
      s_pk[threadIdx.x]  = (unsigned)ctx | ((unsigned)cty << 9) | ((unsigned)r << 17);
      s_inv[threadIdx.x] = P.inv2s2;
      /* does this object's window intersect the block's pixel span? */
      int y0 = p0 / OUT_W;
      int y1 = (p0 + 255) / OUT_W;
      bool two_rows = (y1 > y0);
      int x0 = two_rows ? 0 : (p0 - y0 * OUT_W);
      int x1 = two_rows ? (OUT_W - 1) : (p0 + 255 - y0 * OUT_W);
      bool act = (cty + r >= y0) && (cty - r <= y1) &&
                 (ctx + r >= x0) && (ctx - r <= x1);
      unsigned long long m = __ballot(act);
      if (threadIdx.x == 0) s_mask = m;
    }
    __syncthreads();

    float pos_l = 0.f, neg_l = 0.f, npos = 0.f;
    if (p < HW) {
      float xf = (float)(p % OUT_W);
      float yf = (float)(p / OUT_W);
      float gt = 0.f;
      unsigned long long m = s_mask;       /* wave-uniform loop */
      while (m) {
        int o = __ffsll((unsigned long long)m) - 1;
        m &= m - 1;
        unsigned pk = s_pk[o];
        float inv = s_inv[o];
        float cxv = (float)(pk & 511u);
        float cyv = (float)((pk >> 9) & 255u);
        float rv  = (float)(pk >> 17);
        float dy = yf - cyv;
        float dx = xf - cxv;
        if (fabsf(dy) <= rv && fabsf(dx) <= rv) {
          gt = fmaxf(gt, __expf(-(dy * dy + dx * dx) * inv));
        }
      }
      float x = cls[b * HW + p];
      float pr = 1.f / (1.f + __expf(-x));
      pr = fminf(fmaxf(pr, 1e-4f), 0.9999f);
      if (gt == 1.f) {
        float om = 1.f - pr;
        pos_l = __logf(pr) * om * om;
        npos = 1.f;
      } else {
        float omg = 1.f - gt;
        float w4 = omg * omg;
        w4 *= w4;
        neg_l = __logf(1.f - pr) * pr * pr * w4;
      }
    }

    __shared__ float red[3][4];
    int wid = threadIdx.x >> 6, lane = threadIdx.x & 63;
    float a = waveRedSum(pos_l);
    float c = waveRedSum(neg_l);
    float n = waveRedSum(npos);
    if (lane == 0) { red[0][wid] = a; red[1][wid] = c; red[2][wid] = n; }
    __syncthreads();
    if (threadIdx.x == 0) {
      float pa = 0.f, pc = 0.f, pn = 0.f;
      for (int k = 0; k < 4; ++k) { pa += red[0][k]; pc += red[1][k]; pn += red[2][k]; }
      F[OF_FP + blk * 3 + 0] = pa;
      F[OF_FP + blk * 3 + 1] = pc;
      F[OF_FP + blk * 3 + 2] = pn;
    }
  } else {
    /* ---------- id-loss branch: one block per object ---------- */
    int o = blockIdx.x - NFOCAL;
    int b = o >> 6, i = o & 63;
    PrepOut P = prep_obj(ann1, ann2, b, i);
    if (P.vm == 0.f) {                 /* uniform across block */
      if (threadIdx.x == 0) F[OF_IDNLL + o] = 0.f;
      return;
    }
    int t = threadIdx.x;
    __shared__ float shf[EMB];
    __shared__ float slog[544];
    __shared__ float red4[4];
    int wid = t >> 6, lane = t & 63;

    float f = identis[(size_t)b * EMB * HW + (size_t)t * HW + P.ind];
    float n2 = waveRedSum(f * f);
    if (lane == 0) red4[wid] = n2;
    __syncthreads();
    float norm2 = red4[0] + red4[1] + red4[2] + red4[3];
    const float EMB_SCALE = 1.41421356237309515f * logf(536.0f);
    float scale = EMB_SCALE / fmaxf(sqrtf(norm2), 1e-12f);
    shf[t] = f * scale;
    __syncthreads();

    for (int c = t; c < NID; c += 256) {
      float acc = b_id[c];
      const float* wr = W_id + (size_t)c * EMB;
      #pragma unroll 8
      for (int k = 0; k < EMB; k += 4) {
        float4 wv = *(const float4*)(wr + k);
        float4 sv = *(const float4*)(&shf[k]);
        acc += wv.x * sv.x + wv.y * sv.y + wv.z * sv.z + wv.w * sv.w;
      }
      slog[c] = acc;
    }
    __syncthreads();

    float mx = -1e30f;
    for (int c = t; c < NID; c += 256) mx = fmaxf(mx, slog[c]);
    mx = waveRedMax(mx);
    __syncthreads();
    if (lane == 0) red4[wid] = mx;
    __syncthreads();
    mx = fmaxf(fmaxf(red4[0], red4[1]), fmaxf(red4[2], red4[3]));

    float se = 0.f;
    for (int c = t; c < NID; c += 256) se += __expf(slog[c] - mx);
    se = waveRedSum(se);
    __syncthreads();
    if (lane == 0) red4[wid] = se;
    __syncthreads();

    if (t == 0) {
      float sesum = red4[0] + red4[1] + red4[2] + red4[3];
      float lse = mx + __logf(sesum);
      F[OF_IDNLL + o] = -P.v * (slog[P.id] - lse);
    }
  }
}

__global__ void __launch_bounds__(512)
final_kernel(const float* __restrict__ reg,
             const float* __restrict__ viss,
             const float* __restrict__ ann1,
             const float* __restrict__ ann2,
             const float* __restrict__ F,
             const float* __restrict__ s_det,
             const float* __restrict__ s_id,
             float* __restrict__ out) {
  int t = threadIdx.x;
  int b = t >> 6;           /* wave index = batch */
  int lane = t & 63;

  PrepOut P = prep_obj(ann1, ann2, b, lane);
  float msum = waveRedSum(P.vm);

  float rsum = 0.f, vsum = 0.f;
  if (P.vm > 0.f) {
    for (int c = 0; c < 8; ++c) {
      float pred = reg[(b * 8 + c) * HW + P.ind];
      float d = fabsf(pred - P.wh[c]);
      rsum += (d < 1.f) ? 0.5f * d * d : d - 0.5f;
    }
    float s = 1.f / (1.f + __expf(-viss[b * HW + P.ind]));
    s = fminf(fmaxf(s, 1e-4f), 0.9999f);
    float d = fabsf(s - P.v);
    vsum += (d < 1.f) ? 0.5f * d * d : d - 0.5f;
  }
  rsum = waveRedSum(rsum);
  vsum = waveRedSum(vsum);

  /* focal partial reduce: 162 blocks per batch, strided by lane */
  float pa = 0.f, pc = 0.f, pn = 0.f;
  for (int e = lane; e < NFBLK; e += 64) {
    const float* fp = F + OF_FP + (b * NFBLK + e) * 3;
    pa += fp[0]; pc += fp[1]; pn += fp[2];
  }
  pa = waveRedSum(pa);
  pc = waveRedSum(pc);
  pn = waveRedSum(pn);

  /* id NLL reduce: 64 objects per batch, one per lane */
  float idv = waveRedSum(F[OF_IDNLL + b * 64 + lane]);

  __shared__ float L[8][4];
  if (lane == 0) {
    L[b][0] = (pn > 0.f) ? (-(pa + pc) / fmaxf(pn, 1.f)) : (-pc);
    L[b][1] = rsum / (msum + 0.0001f);
    L[b][2] = vsum / (msum + 0.0001f);
    L[b][3] = idv / fmaxf(msum, 1.f);
  }
  __syncthreads();
  if (t == 0) {
    float cl = 0.f, rl = 0.f, vl = 0.f, il = 0.f;
    for (int k = 0; k < 8; ++k) {
      cl += L[k][0]; rl += L[k][1]; vl += L[k][2]; il += L[k][3];
    }
    out[0] = cl / 8.f;
    out[1] = rl / 8.f;
    out[2] = vl / 8.f;
    out[3] = il / 8.f;
    out[4] = s_det[0];
    out[5] = s_id[0];
  }
}

extern "C" void kernel_launch(void* const* d_in, const int* in_sizes, int n_in,
                              void* d_out, int out_size, void* d_ws, size_t ws_size,
                              hipStream_t stream) {
  const float* cls     = (const float*)d_in[0];
  const float* reg     = (const float*)d_in[1];
  const float* viss    = (const float*)d_in[2];
  const float* identis = (const float*)d_in[3];
  const float* ann1    = (const float*)d_in[4];
  const float* ann2    = (const float*)d_in[5];
  const float* W_id    = (const float*)d_in[6];
  const float* b_id    = (const float*)d_in[7];
  const float* s_det   = (const float*)d_in[8];
  const float* s_id    = (const float*)d_in[9];
  float* F = (float*)d_ws;

  main_kernel<<<NFOCAL + NIDBLK, 256, 0, stream>>>(cls, identis, W_id, b_id,
                                                   ann1, ann2, F);
  final_kernel<<<1, 512, 0, stream>>>(reg, viss, ann1, ann2, F,
                                      s_det, s_id, (float*)d_out);
}